// Round 1
// baseline (156.978 us; speedup 1.0000x reference)
//
#include <hip/hip_runtime.h>
#include <hip/hip_bf16.h>
#include <hip/hip_cooperative_groups.h>

namespace cg = cooperative_groups;

// out = (4096 * (x @ Wv)) @ w_proj + b_proj   [softmax rows sum to 1 =>
// head_w == N_NODES exactly; adj, w_q, w_k never affect the output]
// Wv[d][c=h*128+hd] = w_qkv[2][h][d][hd].  All global tensors fp32.
//
// R6: single cooperative kernel (3 dispatches -> 1).
//  Phase 1a: all threads cvt x fp32 -> xb bf16 (4x bf16x8 each).
//  Phase 1b: each of 1024 waves builds one 16x16 tile of
//            Mt[o][d] = 4096 * (Wv@Wp)^T in bf16 (same MFMA/K-order as R5's
//            32x32 tiles -> bit-identical numerics).
//  grid.sync()  (agent-scope release/acquire covers cross-XCD L2 visibility)
//  Phase 2: out = xb @ Mt^T + bias, R5's proven 64x128-tile 4-wave gemm,
//           block mapping bx=bid&3 (o cols), by=bid>>2 (b rows).
// 256 blocks x 256 threads = 1 small block/CU -> cooperative residency safe.
// Fixed ~40us 256MB ws-poison fill (81-84% HBM peak) is harness-side floor.

constexpr int NNODES = 4096;
constexpr int DIM = 512;

typedef __bf16 bf16x8 __attribute__((ext_vector_type(8)));
typedef float f32x4 __attribute__((ext_vector_type(4)));

__device__ __forceinline__ bf16x8 cvt8(const float* p) {
  const f32x4 lo = *(const f32x4*)p;
  const f32x4 hi = *(const f32x4*)(p + 4);
  bf16x8 r;
#pragma unroll
  for (int j = 0; j < 4; ++j) { r[j] = (__bf16)lo[j]; r[4 + j] = (__bf16)hi[j]; }
  return r;
}

__global__ __launch_bounds__(256) void fused(
    const float* __restrict__ x,
    const float* __restrict__ w_qkv,
    const float* __restrict__ w_proj,
    const float* __restrict__ bias,
    __bf16* __restrict__ Mt,
    __bf16* __restrict__ xb,
    float* __restrict__ out) {
  const int tid = threadIdx.x;
  const int bid = blockIdx.x;
  const int wave = tid >> 6, lane = tid & 63;
  const int ln = lane & 15, q = lane >> 4;

  // ---- Phase 1a: xb = (bf16)x. 65536 threads x 32 elems. ----
  {
    const int gt = bid * 256 + tid;
#pragma unroll
    for (int j = 0; j < 4; ++j) {
      const size_t i8 = (size_t)(j * 65536 + gt) * 8;
      *(bf16x8*)&xb[i8] = cvt8(&x[i8]);
    }
  }

  // ---- Phase 1b: one 16x16 Mt tile per wave (1024 waves = 32x32 tiles). ----
  {
    const int wid = bid * 4 + wave;            // [0,1024)
    const int o0 = (wid >> 5) * 16;            // o rows of Mt
    const int d0 = (wid & 31) * 16;            // d cols of Mt
    const float* __restrict__ wv = w_qkv + 2 * 4 * DIM * 128;  // v slice

    f32x4 acc = {};
#pragma unroll
    for (int k0 = 0; k0 < DIM; k0 += 32) {     // k = c (h*128+hd)
      const int h = k0 >> 7, hb = k0 & 127;
      float raw[8];
#pragma unroll
      for (int j = 0; j < 8; ++j)
        raw[j] = w_proj[(k0 + q * 8 + j) * DIM + o0 + ln];
      bf16x8 af, bf;
#pragma unroll
      for (int j = 0; j < 8; ++j) af[j] = (__bf16)raw[j];
      bf = cvt8(&wv[((size_t)h * DIM + d0 + ln) * 128 + hb + q * 8]);
      acc = __builtin_amdgcn_mfma_f32_16x16x32_bf16(af, bf, acc, 0, 0, 0);
    }
#pragma unroll
    for (int r = 0; r < 4; ++r)
      Mt[(o0 + q * 4 + r) * DIM + d0 + ln] = (__bf16)(acc[r] * (float)NNODES);
  }

  cg::this_grid().sync();

  // ---- Phase 2: out[b][o] = sum_d xb[b][d]*Mt[o][d] + bias[o]. ----
  {
    const int m0 = (bid >> 2) * 64 + (wave >> 1) * 32;    // b rows
    const int n0 = (bid & 3) * 128 + (wave & 1) * 64;     // o cols

    f32x4 acc[2][4] = {};

#pragma unroll 4
    for (int k0 = 0; k0 < DIM; k0 += 32) {
      bf16x8 af[2], bf[4];
#pragma unroll
      for (int mi = 0; mi < 2; ++mi)
        af[mi] = *(const bf16x8*)&xb[(size_t)(m0 + mi * 16 + ln) * DIM + k0 + q * 8];
#pragma unroll
      for (int ni = 0; ni < 4; ++ni)
        bf[ni] = *(const bf16x8*)&Mt[(size_t)(n0 + ni * 16 + ln) * DIM + k0 + q * 8];
#pragma unroll
      for (int mi = 0; mi < 2; ++mi)
#pragma unroll
        for (int ni = 0; ni < 4; ++ni)
          acc[mi][ni] = __builtin_amdgcn_mfma_f32_16x16x32_bf16(
              af[mi], bf[ni], acc[mi][ni], 0, 0, 0);
    }

#pragma unroll
    for (int ni = 0; ni < 4; ++ni) {
      const int o = n0 + ni * 16 + ln;
      const float bj = bias[o];
#pragma unroll
      for (int mi = 0; mi < 2; ++mi)
#pragma unroll
        for (int r = 0; r < 4; ++r) {
          const int b = m0 + mi * 16 + q * 4 + r;
          out[(size_t)b * DIM + o] = acc[mi][ni][r] + bj;
        }
    }
  }
}

extern "C" void kernel_launch(void* const* d_in, const int* in_sizes, int n_in,
                              void* d_out, int out_size, void* d_ws, size_t ws_size,
                              hipStream_t stream) {
  const float* x      = (const float*)d_in[0];
  // d_in[1] = adj — irrelevant (softmax rows sum to 1), never read
  const float* w_qkv  = (const float*)d_in[2];
  const float* w_proj = (const float*)d_in[3];
  const float* b_proj = (const float*)d_in[4];
  __bf16* Mt = (__bf16*)d_ws;                          // 512 KB
  __bf16* xb = (__bf16*)((char*)d_ws + DIM * DIM * 2); // 4 MB, 16B-aligned
  float* out = (float*)d_out;                          // 4096*512 fp32

  void* args[] = {(void*)&x, (void*)&w_qkv, (void*)&w_proj, (void*)&b_proj,
                  (void*)&Mt, (void*)&xb, (void*)&out};
  hipLaunchCooperativeKernel((const void*)fused, dim3(256), dim3(256),
                             args, 0, stream);
}

// Round 2
// 129.141 us; speedup vs baseline: 1.2156x; 1.2156x over previous
//
#include <hip/hip_runtime.h>
#include <hip/hip_bf16.h>

// out = (4096 * (x @ Wv)) @ w_proj + b_proj   [softmax rows sum to 1 =>
// head_w == N_NODES exactly; adj, w_q, w_k never affect the output]
// Wv[d][c=h*128+hd] = w_qkv[2][h][d][hd].  All global tensors fp32.
//
// R7: two dispatches, no grid barrier (R6's coop grid.sync spun ~38us).
//  1) build_Mt: Mt[o][d] = 4096 * (Wv@Wp)^T, bf16 (R5's proven kernel).
//  2) gemm_out: out = x @ Mt^T + b. A-fragments converted fp32->bf16
//     IN-REGISTER per K-iter (16 packed cvts vs 8 MFMAs; VALU was ~4% busy)
//     -> cvt_x dispatch and all xb workspace traffic eliminated.
// Numerics identical to R5 (same bf16 rounding, same MFMA order).
// Fixed ~40-50us 256MB ws-poison fill (81-84% HBM peak) is harness-side floor.

constexpr int NNODES = 4096;
constexpr int DIM = 512;

typedef __bf16 bf16x8 __attribute__((ext_vector_type(8)));
typedef float f32x4 __attribute__((ext_vector_type(4)));

__device__ __forceinline__ bf16x8 cvt8(const float* p) {
  const f32x4 lo = *(const f32x4*)p;
  const f32x4 hi = *(const f32x4*)(p + 4);
  bf16x8 r;
#pragma unroll
  for (int j = 0; j < 4; ++j) { r[j] = (__bf16)lo[j]; r[4 + j] = (__bf16)hi[j]; }
  return r;
}

// ---------------------------------------------------------------------------
// Kernel 1: Mt[o][d] = 4096 * sum_c Wp[c][o] * Wv[d][c], bf16.
// One wave per 32(o) x 32(d) tile. Grid 16x16 = 256 single-wave blocks.
// ---------------------------------------------------------------------------
__global__ __launch_bounds__(64) void build_Mt(
    const float* __restrict__ w_qkv,
    const float* __restrict__ w_proj,
    __bf16* __restrict__ Mt) {
  const int lane = threadIdx.x;
  const int ln = lane & 15, q = lane >> 4;
  const int m0 = blockIdx.y * 32;   // o rows of Mt
  const int n0 = blockIdx.x * 32;   // d cols of Mt
  const float* __restrict__ wv = w_qkv + 2 * 4 * DIM * 128;  // v slice

  f32x4 acc[2][2] = {};

#pragma unroll
  for (int k0 = 0; k0 < DIM; k0 += 32) {   // k = c (h*128+hd)
    const int h = k0 >> 7, hb = k0 & 127;
    bf16x8 af[2], bf[2];
#pragma unroll
    for (int mi = 0; mi < 2; ++mi) {
      float raw[8];
#pragma unroll
      for (int j = 0; j < 8; ++j)
        raw[j] = w_proj[(k0 + q * 8 + j) * DIM + (m0 + mi * 16 + ln)];
#pragma unroll
      for (int j = 0; j < 8; ++j) af[mi][j] = (__bf16)raw[j];
    }
#pragma unroll
    for (int ni = 0; ni < 2; ++ni)
      bf[ni] = cvt8(&wv[((size_t)h * DIM + (n0 + ni * 16 + ln)) * 128 + hb + q * 8]);
#pragma unroll
    for (int mi = 0; mi < 2; ++mi)
#pragma unroll
      for (int ni = 0; ni < 2; ++ni)
        acc[mi][ni] = __builtin_amdgcn_mfma_f32_16x16x32_bf16(
            af[mi], bf[ni], acc[mi][ni], 0, 0, 0);
  }

#pragma unroll
  for (int mi = 0; mi < 2; ++mi)
#pragma unroll
    for (int ni = 0; ni < 2; ++ni)
#pragma unroll
      for (int r = 0; r < 4; ++r) {
        const int o = m0 + mi * 16 + q * 4 + r;
        const int d = n0 + ni * 16 + ln;
        Mt[o * DIM + d] = (__bf16)(acc[mi][ni][r] * (float)NNODES);
      }
}

// ---------------------------------------------------------------------------
// Kernel 2: out[b][o] = sum_d (bf16)x[b][d] * Mt[o][d] + bias[o], fp32 out.
// 256 threads = 4 waves (2m x 2n); wave tile 32(b) x 64(o); block 64x128.
// Grid (512/128) x (4096/64) = 4 x 64 = 256 blocks.
// A-frags: load 2x f32x4 of x and cvt in-register (no xb intermediate).
// ---------------------------------------------------------------------------
__global__ __launch_bounds__(256) void gemm_out(
    const float* __restrict__ x,
    const __bf16* __restrict__ Mt,
    const float* __restrict__ bias,
    float* __restrict__ out) {
  const int tid = threadIdx.x;
  const int wave = tid >> 6, lane = tid & 63;
  const int ln = lane & 15, q = lane >> 4;
  const int m0 = blockIdx.y * 64 + (wave >> 1) * 32;   // b rows
  const int n0 = blockIdx.x * 128 + (wave & 1) * 64;   // o cols

  f32x4 acc[2][4] = {};

#pragma unroll 4
  for (int k0 = 0; k0 < DIM; k0 += 32) {
    bf16x8 af[2], bf[4];
#pragma unroll
    for (int mi = 0; mi < 2; ++mi)
      af[mi] = cvt8(&x[(size_t)(m0 + mi * 16 + ln) * DIM + k0 + q * 8]);
#pragma unroll
    for (int ni = 0; ni < 4; ++ni)
      bf[ni] = *(const bf16x8*)&Mt[(size_t)(n0 + ni * 16 + ln) * DIM + k0 + q * 8];
#pragma unroll
    for (int mi = 0; mi < 2; ++mi)
#pragma unroll
      for (int ni = 0; ni < 4; ++ni)
        acc[mi][ni] = __builtin_amdgcn_mfma_f32_16x16x32_bf16(
            af[mi], bf[ni], acc[mi][ni], 0, 0, 0);
  }

#pragma unroll
  for (int ni = 0; ni < 4; ++ni) {
    const int o = n0 + ni * 16 + ln;
    const float bj = bias[o];
#pragma unroll
    for (int mi = 0; mi < 2; ++mi)
#pragma unroll
      for (int r = 0; r < 4; ++r) {
        const int b = m0 + mi * 16 + q * 4 + r;
        out[(size_t)b * DIM + o] = acc[mi][ni][r] + bj;
      }
  }
}

extern "C" void kernel_launch(void* const* d_in, const int* in_sizes, int n_in,
                              void* d_out, int out_size, void* d_ws, size_t ws_size,
                              hipStream_t stream) {
  const float* x      = (const float*)d_in[0];
  // d_in[1] = adj — irrelevant (softmax rows sum to 1), never read
  const float* w_qkv  = (const float*)d_in[2];
  const float* w_proj = (const float*)d_in[3];
  const float* b_proj = (const float*)d_in[4];
  __bf16* Mt = (__bf16*)d_ws;                          // 512 KB
  float* out = (float*)d_out;                          // 4096*512 fp32

  build_Mt<<<dim3(DIM / 32, DIM / 32), 64, 0, stream>>>(w_qkv, w_proj, Mt);
  gemm_out<<<dim3(DIM / 128, NNODES / 64), 256, 0, stream>>>(x, Mt, b_proj, out);
}